// Round 19
// baseline (195.032 us; speedup 1.0000x reference)
//
#include <hip/hip_runtime.h>
#include <hip/hip_bf16.h>

#define NQ 4096
#define EMBED 256
#define HEADS 8
#define HEAD_DIM 32
#define LEVELS 4
#define POINTS 8
#define CAMS 6
#define LTOT 19560
#define MROWS (CAMS * LTOT)   // 117360

using bf16x8 = __attribute__((ext_vector_type(8))) __bf16;
using bf16x4 = __attribute__((ext_vector_type(4))) __bf16;
using f32x4v = __attribute__((ext_vector_type(4))) float;
using f32x2v = __attribute__((ext_vector_type(2))) float;

__device__ inline ushort f2bf(float f) {
    unsigned u = __builtin_bit_cast(unsigned, f);
    u += 0x7FFFu + ((u >> 16) & 1u);   // round-to-nearest-even
    return (ushort)(u >> 16);
}
__device__ inline float bflo(unsigned u) {
    return __builtin_bit_cast(float, u << 16);
}
__device__ inline float bfhi(unsigned u) {
    return __builtin_bit_cast(float, u & 0xFFFF0000u);
}
__device__ inline float bpermf(int addr, float v) {
    return __builtin_bit_cast(float, __builtin_amdgcn_ds_bpermute(addr, __builtin_bit_cast(int, v)));
}
__device__ inline unsigned bpermu(int addr, unsigned v) {
    return (unsigned)__builtin_amdgcn_ds_bpermute(addr, (int)v);
}
// fp8 e4m3 (OCP on gfx950) HW converts
__device__ inline unsigned char f2fp8(float f) {
    return (unsigned char)(__builtin_amdgcn_cvt_pk_fp8_f32(f, 0.f, 0, false) & 0xFF);
}

// ---------------------------------------------------------------------------
// Detect bev_mask element size (uint8 bools vs int32).
// ---------------------------------------------------------------------------
__global__ __launch_bounds__(256) void detect_kernel(const unsigned int* __restrict__ bm,
                                                     unsigned int* __restrict__ flag) {
    __shared__ unsigned int red[256];
    const int t = threadIdx.x;
    unsigned int acc = 0;
    for (int i = t; i < (CAMS * NQ * 4) / 4; i += 256)
        acc |= (bm[i] & 0xFFFFFF00u);
    red[t] = acc;
    __syncthreads();
    for (int s = 128; s > 0; s >>= 1) {
        if (t < s) red[t] |= red[t + s];
        __syncthreads();
    }
    if (t == 0) flag[0] = red[0] ? 1u : 0u;
}

__global__ __launch_bounds__(256) void mask_kernel(const void* __restrict__ bm,
                                                   const unsigned int* __restrict__ flag,
                                                   float* __restrict__ maskf,
                                                   float* __restrict__ countf) {
    const int q = blockIdx.x * 256 + threadIdx.x;
    if (q >= NQ) return;
    const bool u8 = (flag[0] != 0);
    float cnt = 0.f;
    #pragma unroll
    for (int c = 0; c < CAMS; c++) {
        bool hit;
        if (u8) {
            const unsigned int w = ((const unsigned int*)bm)[c * NQ + q];
            hit = (w != 0);
        } else {
            const int* p = (const int*)bm;
            int s = 0;
            #pragma unroll
            for (int d = 0; d < 4; d++) s |= p[(c * NQ + q) * 4 + d];
            hit = (s != 0);
        }
        maskf[c * NQ + q] = hit ? 1.f : 0.f;
        cnt += hit ? 1.f : 0.f;
    }
    countf[q] = fmaxf(cnt, 1.f);
}

// ---------------------------------------------------------------------------
// Build WTall [1280][256] bf16: transposed cols of (W_off | W_attn | W_out |
// W_value).
// ---------------------------------------------------------------------------
__global__ __launch_bounds__(256) void wtall_kernel(const float* __restrict__ W_off,
                                                    const float* __restrict__ W_attn,
                                                    const float* __restrict__ W_out,
                                                    const float* __restrict__ W_value,
                                                    ushort* __restrict__ WTall) {
    __shared__ float tile[32][33];
    const int bn = blockIdx.x;   // 40 n-tiles
    const int bk = blockIdx.y;   // 8 k-tiles
    const int t = threadIdx.x;
    const int r = t >> 5, c = t & 31;
    #pragma unroll
    for (int it = 0; it < 4; it++) {
        const int k = bk * 32 + it * 8 + r;
        const int n = bn * 32 + c;
        float v;
        if (n < 512)       v = W_off[(size_t)k * 512 + n];
        else if (n < 768)  v = W_attn[(size_t)k * 256 + (n - 512)];
        else if (n < 1024) v = W_out[(size_t)k * 256 + (n - 768)];
        else               v = W_value[(size_t)k * 256 + (n - 1024)];
        tile[it * 8 + r][c] = v;
    }
    __syncthreads();
    #pragma unroll
    for (int it = 0; it < 4; it++) {
        const int n = bn * 32 + it * 8 + r;
        const int k = bk * 32 + c;
        WTall[(size_t)n * 256 + k] = f2bf(tile[c][it * 8 + r]);
    }
}

// ---------------------------------------------------------------------------
// proj GEMM: logits[4096][768] = query @ (W_off|W_attn), raw.
// ---------------------------------------------------------------------------
#define LDT 40   // padded LDS stride (bf16)

__global__ __launch_bounds__(256) void proj_gemm(const float* __restrict__ A,
                                                 const ushort* __restrict__ WT,
                                                 float* __restrict__ C) {
    __shared__ ushort As[128 * LDT];
    __shared__ ushort Bs[128 * LDT];
    const int t = threadIdx.x;
    const int wave = t >> 6, lane = t & 63;
    const int wm = (wave & 1) * 64, wn = (wave >> 1) * 64;
    const int n0 = blockIdx.x * 128, m0 = blockIdx.y * 128;
    const int fl = lane & 15, fk = (lane >> 4) * 8;
    const int sr = t >> 1, sk = (t & 1) * 16;

    const float*  arow = A  + (size_t)(m0 + sr) * 256;
    const ushort* brow = WT + (size_t)(n0 + sr) * 256;

    f32x4v acc[4][4];
    #pragma unroll
    for (int i = 0; i < 4; i++)
        #pragma unroll
        for (int j = 0; j < 4; j++) acc[i][j] = (f32x4v)(0.f);

    for (int k0 = 0; k0 < 256; k0 += 32) {
        bf16x8 w0, w1;
        #pragma unroll
        for (int u = 0; u < 2; u++) {
            const float4 v = *(const float4*)&arow[k0 + sk + u * 4];
            w0[u * 4 + 0] = (__bf16)v.x; w0[u * 4 + 1] = (__bf16)v.y;
            w0[u * 4 + 2] = (__bf16)v.z; w0[u * 4 + 3] = (__bf16)v.w;
        }
        #pragma unroll
        for (int u = 0; u < 2; u++) {
            const float4 v = *(const float4*)&arow[k0 + sk + 8 + u * 4];
            w1[u * 4 + 0] = (__bf16)v.x; w1[u * 4 + 1] = (__bf16)v.y;
            w1[u * 4 + 2] = (__bf16)v.z; w1[u * 4 + 3] = (__bf16)v.w;
        }
        *(bf16x8*)&As[sr * LDT + sk]     = w0;
        *(bf16x8*)&As[sr * LDT + sk + 8] = w1;
        const uint4* bp = (const uint4*)&brow[k0 + sk];
        *(uint4*)&Bs[sr * LDT + sk]     = bp[0];
        *(uint4*)&Bs[sr * LDT + sk + 8] = bp[1];
        __syncthreads();

        bf16x8 af[4], bfv[4];
        #pragma unroll
        for (int i = 0; i < 4; i++)
            af[i] = *(const bf16x8*)&As[(wm + i * 16 + fl) * LDT + fk];
        #pragma unroll
        for (int j = 0; j < 4; j++)
            bfv[j] = *(const bf16x8*)&Bs[(wn + j * 16 + fl) * LDT + fk];
        #pragma unroll
        for (int i = 0; i < 4; i++)
            #pragma unroll
            for (int j = 0; j < 4; j++)
                acc[i][j] = __builtin_amdgcn_mfma_f32_16x16x32_bf16(af[i], bfv[j], acc[i][j], 0, 0, 0);
        __syncthreads();
    }

    const int rb = (lane >> 4) * 4;
    #pragma unroll
    for (int j = 0; j < 4; j++) {
        const int col = n0 + wn + j * 16 + fl;
        #pragma unroll
        for (int i = 0; i < 4; i++)
            #pragma unroll
            for (int r = 0; r < 4; r++)
                C[(size_t)(m0 + wm + i * 16 + rb + r) * 768 + col] = acc[i][j][r];
    }
}

// ---------------------------------------------------------------------------
// proj epilogue: offset normalize + per-head softmax. 4 queries/block.
// ---------------------------------------------------------------------------
__global__ __launch_bounds__(256) void proj_epi(const float* __restrict__ logits,
                                                const float* __restrict__ b_off,
                                                const float* __restrict__ b_attn,
                                                float* __restrict__ offn,
                                                float* __restrict__ attnw) {
    const int t = threadIdx.x;
    const int q0 = blockIdx.x * 4;
    const float Wl[4] = {160.f, 80.f, 40.f, 20.f};
    const float Hl[4] = {92.f, 46.f, 23.f, 12.f};
    const int j0 = t, j1 = t + 256;
    const int l0 = (j0 & 63) >> 4, l1 = (j1 & 63) >> 4;
    const float inv0 = 1.0f / ((j0 & 1) ? Hl[l0] : Wl[l0]);
    const float inv1 = 1.0f / ((j1 & 1) ? Hl[l1] : Wl[l1]);
    const float bo0 = b_off[j0], bo1 = b_off[j1], ba = b_attn[t];
    #pragma unroll
    for (int i = 0; i < 4; i++) {
        const float* lg = logits + (size_t)(q0 + i) * 768;
        offn[(size_t)(q0 + i) * 512 + j0] = (lg[j0] + bo0) * inv0;
        offn[(size_t)(q0 + i) * 512 + j1] = (lg[j1] + bo1) * inv1;
        const float v = lg[512 + t] + ba;
        float m = v;
        for (int s = 16; s > 0; s >>= 1) m = fmaxf(m, __shfl_xor(m, s, 32));
        const float e = expf(v - m);
        float ssum = e;
        for (int s = 16; s > 0; s >>= 1) ssum += __shfl_xor(ssum, s, 32);
        attnw[(size_t)(q0 + i) * 256 + t] = e / ssum;
    }
}

// ---------------------------------------------------------------------------
// Value projection GEMM (r17 structure) -> FP8 e4m3 val in HEAD-MAJOR layout
// val[cam][head][pixel][32ch]: x-corner pairs of a sampling point become
// consecutive 32B rows (same/adjacent 64B line) -> ~25% less L2-miss
// traffic in sample. Coalesced one-shot A stage, swizzled LDS, B dbuf,
// one barrier/K-step, LDS fp8 pack + 32B-chunk copy-out (chunk = one
// head's channels -> one contiguous 32B row in the new layout).
// ---------------------------------------------------------------------------
#define GMT 64

__global__ __launch_bounds__(256) void gemm_mfma(const float* __restrict__ A,
                                                 const ushort* __restrict__ WT,
                                                 const float* __restrict__ bias,
                                                 unsigned char* __restrict__ C, int M) {
    __shared__ ushort AsF[GMT * 256];    // 32KB bf16, swizzled; reused as fp8 image
    __shared__ ushort Bsb[2][128 * 32];  // 2 x 8KB bf16, swizzled
    const int t = threadIdx.x;
    const int wave = t >> 6, lane = t & 63;
    const int wm = (wave & 1) * 32, wn = (wave >> 1) * 64;

    // XCD-pair swizzle: blocks w and w+8 (same XCD) = two n-halves of one m-tile
    const int w = blockIdx.x;
    int mt, nh;
    if (w < 3664) { mt = (w >> 4) * 8 + (w & 7); nh = (w >> 3) & 1; }
    else          { mt = 1832 + ((w - 3664) >> 1); nh = (w - 3664) & 1; }
    const int m0 = mt * GMT, n0 = nh * 128;

    const int fl = lane & 15, fk = (lane >> 4) * 8;

    // ---- A stage: 16 rounds, each 256 threads x 16B contiguous ----
    #pragma unroll 4
    for (int r = 0; r < 16; r++) {
        const int e = r * 1024 + t * 4;          // ushort idx in [64][256] tile
        const int row = e >> 8;
        int gr = m0 + row; if (gr >= M) gr = M - 1;
        const float4 v = *(const float4*)&A[(size_t)gr * 256 + (e & 255)];
        bf16x4 pk;
        pk[0] = (__bf16)v.x; pk[1] = (__bf16)v.y;
        pk[2] = (__bf16)v.z; pk[3] = (__bf16)v.w;
        *(bf16x4*)&AsF[e ^ ((row & 7) << 3)] = pk;
    }

    // ---- B stage buf0 (k0 = 0) ----
    const int rr = t >> 1, off = (t & 1) * 16;
    const ushort* bsrc = WT + (size_t)(n0 + rr) * 256 + off;
    const int bsw = (rr & 3) << 3;
    {
        const uint4 b0 = *(const uint4*)(bsrc);
        const uint4 b1 = *(const uint4*)(bsrc + 8);
        *(uint4*)&Bsb[0][(rr * 32 + off + 0) ^ bsw] = b0;
        *(uint4*)&Bsb[0][(rr * 32 + off + 8) ^ bsw] = b1;
    }
    __syncthreads();

    f32x4v acc[2][4];
    #pragma unroll
    for (int i = 0; i < 2; i++)
        #pragma unroll
        for (int j = 0; j < 4; j++) acc[i][j] = (f32x4v)(0.f);

    #pragma unroll
    for (int ks = 0; ks < 8; ks++) {
        const int cur = ks & 1;
        const int k0 = ks * 32;

        uint4 nb0, nb1;
        if (ks < 7) {
            nb0 = *(const uint4*)(bsrc + (k0 + 32));
            nb1 = *(const uint4*)(bsrc + (k0 + 32) + 8);
        }

        bf16x8 af[2], bfv[4];
        #pragma unroll
        for (int i = 0; i < 2; i++) {
            const int row = wm + i * 16 + fl;
            af[i] = *(const bf16x8*)&AsF[(row * 256 + k0 + fk) ^ ((fl & 7) << 3)];
        }
        #pragma unroll
        for (int j = 0; j < 4; j++) {
            const int br = wn + j * 16 + fl;
            bfv[j] = *(const bf16x8*)&Bsb[cur][(br * 32 + fk) ^ ((fl & 3) << 3)];
        }
        #pragma unroll
        for (int i = 0; i < 2; i++)
            #pragma unroll
            for (int j = 0; j < 4; j++)
                acc[i][j] = __builtin_amdgcn_mfma_f32_16x16x32_bf16(af[i], bfv[j], acc[i][j], 0, 0, 0);

        if (ks < 7) {
            *(uint4*)&Bsb[cur ^ 1][(rr * 32 + off + 0) ^ bsw] = nb0;
            *(uint4*)&Bsb[cur ^ 1][(rr * 32 + off + 8) ^ bsw] = nb1;
        }
        __syncthreads();
    }

    // ---- epilogue: pack fp8 into LDS image [64 rows][136 B stride] ----
    unsigned char* img = (unsigned char*)AsF;   // 64*136 = 8704 B <= 32 KB
    const int rb = (lane >> 4) * 4;
    #pragma unroll
    for (int j = 0; j < 4; j++) {
        const int col = wn + j * 16 + fl;
        const float bv = bias[n0 + col];
        #pragma unroll
        for (int i = 0; i < 2; i++) {
            #pragma unroll
            for (int r = 0; r < 4; r++) {
                const int row = wm + i * 16 + rb + r;
                img[row * 136 + col] = f2fp8(acc[i][j][r] + bv);
            }
        }
    }
    __syncthreads();

    // ---- copy-out to head-major layout: chunk = one head's 32 channels ----
    {
        const int row = t >> 2, cb = (t & 3) * 32;
        const int grow = m0 + row;
        if (grow < M) {
            const int cam = grow / LTOT;            // magic-mul division
            const int pix = grow - cam * LTOT;
            const int hh  = (n0 + cb) >> 5;
            const uint4 w0v = *(const uint4*)&img[row * 136 + cb];
            const uint4 w1v = *(const uint4*)&img[row * 136 + cb + 16];
            unsigned char* dst = C + ((size_t)(cam * HEADS + hh) * LTOT + pix) * 32;
            *(uint4*)dst = w0v;
            *(uint4*)(dst + 16) = w1v;
        }
    }
}

// ---------------------------------------------------------------------------
// Sampling helpers (inline, fully unrolled -> registers).
// ---------------------------------------------------------------------------
__device__ __forceinline__ void bperm_batch(int aP0, int aP1,
                                            const float* wts, const unsigned* rowB,
                                            float* w, unsigned* ro) {
    #pragma unroll
    for (int c = 0; c < 4; c++) {
        w[c]     = bpermf(aP0, wts[c]);
        ro[c]    = bpermu(aP0, rowB[c]);
        w[4 + c] = bpermf(aP1, wts[c]);
        ro[4 + c] = bpermu(aP1, rowB[c]);
    }
}
__device__ __forceinline__ void load_batch8(const char* base, const unsigned* ro, unsigned* vv) {
    #pragma unroll
    for (int c = 0; c < 8; c++)
        vv[c] = *(const unsigned*)(base + ro[c]);
}
__device__ __forceinline__ void acc_batch8(const float* w, const unsigned* vv,
                                           float2& a01, float2& a23) {
    #pragma unroll
    for (int c = 0; c < 8; c++) {
        const float wt = w[c];
        const f32x2v lo = __builtin_amdgcn_cvt_pk_f32_fp8(vv[c], false);
        const f32x2v hi = __builtin_amdgcn_cvt_pk_f32_fp8(vv[c], true);
        a01.x += wt * lo.x; a01.y += wt * lo.y;
        a23.x += wt * hi.x; a23.y += wt * hi.y;
    }
}

// ---------------------------------------------------------------------------
// Deformable bilinear sampling over FP8 val (HEAD-MAJOR layout).
// One WAVE per (cam,q): 8 heads x 8 lanes, lane owns 4 channels (4B gathers
// at rowB = pixel*32 within the (cam,head) plane). bpermute-deduped weight
// math + 2-stage pipelined batches.
// ---------------------------------------------------------------------------
__global__ __launch_bounds__(256) void sample_kernel(const float* __restrict__ refp,
                                                     const float* __restrict__ offn,
                                                     const float* __restrict__ attnw,
                                                     const unsigned char* __restrict__ val,
                                                     const float* __restrict__ maskf,
                                                     ushort* __restrict__ out_cam) {
    const int wv = threadIdx.x >> 6, lane = threadIdx.x & 63;
    const int pair = blockIdx.x * 4 + wv;
    const int cam = pair >> 12;
    const int q = pair & (NQ - 1);

    const int h = lane >> 3, dg = lane & 7;
    ushort* dst = &out_cam[((size_t)cam * NQ + q) * EMBED + h * HEAD_DIM + dg * 4];
    const float mk = maskf[cam * NQ + q];
    if (mk == 0.f) {                       // wave-uniform
        ushort4 z; z.x = 0; z.y = 0; z.z = 0; z.w = 0;
        *(ushort4*)dst = z;
        return;
    }

    const float* refq = refp + ((size_t)cam * NQ + q) * 8;
    const float* offq = offn + (size_t)q * 512 + h * 64;
    const float* attq = attnw + (size_t)q * 256 + h * 32;
    // (cam,head) plane base + lane channel offset
    const char* camLane = (const char*)val
        + ((size_t)(cam * HEADS + h) * LTOT) * 32 + dg * 4;

    const float rx = refq[2 * (dg & 3)], ry = refq[2 * (dg & 3) + 1];
    const int grp4 = (lane & 56) * 4;      // bpermute byte-addr base of group

    const int Hs[4] = {92, 46, 23, 12};
    const int Ws[4] = {160, 80, 40, 20};
    const int st[4] = {0, 14720, 18400, 19320};

    float2 a01 = {0.f, 0.f}, a23 = {0.f, 0.f};
    #pragma unroll
    for (int l = 0; l < LEVELS; l++) {
        const int H = Hs[l], W = Ws[l];
        const float fW = (float)W, fH = (float)H;

        // ---- own-point weight/address compute (1 point per lane) ----
        float wts[4];
        unsigned rowB[4];
        {
            const float x = (rx + offq[l * 16 + dg * 2]) * fW - 0.5f;
            const float y = (ry + offq[l * 16 + dg * 2 + 1]) * fH - 0.5f;
            const float x0f = floorf(x), y0f = floorf(y);
            const float lx = x - x0f, ly = y - y0f;
            const int x0 = (int)x0f, y0 = (int)y0f, x1 = x0 + 1, y1 = y0 + 1;
            const float aw = attq[l * 8 + dg];
            const bool vx0 = (unsigned)x0 < (unsigned)W;
            const bool vx1 = (unsigned)x1 < (unsigned)W;
            const bool vy0 = (unsigned)y0 < (unsigned)H;
            const bool vy1 = (unsigned)y1 < (unsigned)H;
            const float hx = lx * aw, gx = aw - hx;
            wts[0] = (vx0 & vy0) ? gx * (1.f - ly) : 0.f;
            wts[1] = (vx1 & vy0) ? hx * (1.f - ly) : 0.f;
            wts[2] = (vx0 & vy1) ? gx * ly : 0.f;
            wts[3] = (vx1 & vy1) ? hx * ly : 0.f;
            const int cx0 = min(max(x0, 0), W - 1), cx1 = min(max(x1, 0), W - 1);
            const int cy0 = min(max(y0, 0), H - 1), cy1 = min(max(y1, 0), H - 1);
            const unsigned r0 = (unsigned)(st[l] + cy0 * W), r1 = (unsigned)(st[l] + cy1 * W);
            rowB[0] = (r0 + cx0) * 32;
            rowB[1] = (r0 + cx1) * 32;
            rowB[2] = (r1 + cx0) * 32;
            rowB[3] = (r1 + cx1) * 32;
        }

        // ---- 2-stage pipelined batches: issue next before accumulating ----
        float w0[8], w1[8];
        unsigned ro0[8], ro1[8];
        unsigned vv0[8], vv1[8];

        bperm_batch(grp4 + 0 * 4, grp4 + 1 * 4, wts, rowB, w0, ro0);  // pts 0,1
        load_batch8(camLane, ro0, vv0);
        bperm_batch(grp4 + 2 * 4, grp4 + 3 * 4, wts, rowB, w1, ro1);  // pts 2,3
        load_batch8(camLane, ro1, vv1);
        acc_batch8(w0, vv0, a01, a23);
        bperm_batch(grp4 + 4 * 4, grp4 + 5 * 4, wts, rowB, w0, ro0);  // pts 4,5
        load_batch8(camLane, ro0, vv0);
        acc_batch8(w1, vv1, a01, a23);
        bperm_batch(grp4 + 6 * 4, grp4 + 7 * 4, wts, rowB, w1, ro1);  // pts 6,7
        load_batch8(camLane, ro1, vv1);
        acc_batch8(w0, vv0, a01, a23);
        acc_batch8(w1, vv1, a01, a23);
    }
    ushort4 o;
    o.x = __builtin_bit_cast(ushort, (__bf16)a01.x);
    o.y = __builtin_bit_cast(ushort, (__bf16)a01.y);
    o.z = __builtin_bit_cast(ushort, (__bf16)a23.x);
    o.w = __builtin_bit_cast(ushort, (__bf16)a23.y);
    *(ushort4*)dst = o;
}

// ---------------------------------------------------------------------------
// Masked mean over cams (bf16 out_cam) -> Sbf bf16. One wave per query.
// ---------------------------------------------------------------------------
__global__ __launch_bounds__(256) void mean_kernel(const ushort* __restrict__ out_cam,
                                                   const float* __restrict__ maskf,
                                                   const float* __restrict__ countf,
                                                   ushort* __restrict__ Sbf) {
    const int wv = threadIdx.x >> 6, lane = threadIdx.x & 63;
    const int q = blockIdx.x * 4 + wv;
    const int c4 = lane * 4;
    float4 acc = make_float4(0.f, 0.f, 0.f, 0.f);
    #pragma unroll
    for (int c = 0; c < CAMS; c++) {
        const float m = maskf[c * NQ + q];
        const uint2 v = *(const uint2*)&out_cam[(((size_t)c * NQ + q) << 8) + c4];
        acc.x += m * bflo(v.x); acc.y += m * bfhi(v.x);
        acc.z += m * bflo(v.y); acc.w += m * bfhi(v.y);
    }
    const float inv = 1.0f / countf[q];
    ushort4 s;
    s.x = __builtin_bit_cast(ushort, (__bf16)(acc.x * inv));
    s.y = __builtin_bit_cast(ushort, (__bf16)(acc.y * inv));
    s.z = __builtin_bit_cast(ushort, (__bf16)(acc.z * inv));
    s.w = __builtin_bit_cast(ushort, (__bf16)(acc.w * inv));
    *(ushort4*)&Sbf[(size_t)q * 256 + c4] = s;
}

// ---------------------------------------------------------------------------
// Output GEMM: out = Sbf @ W_out + b_out + query.
// ---------------------------------------------------------------------------
__global__ __launch_bounds__(256) void out_gemm(const ushort* __restrict__ A,
                                                const ushort* __restrict__ WT,
                                                const float* __restrict__ bias,
                                                const float* __restrict__ query,
                                                float* __restrict__ out) {
    __shared__ ushort As[128 * LDT];
    __shared__ ushort Bs[128 * LDT];
    const int t = threadIdx.x;
    const int wave = t >> 6, lane = t & 63;
    const int wm = (wave & 1) * 64, wn = (wave >> 1) * 64;
    const int n0 = blockIdx.x * 128, m0 = blockIdx.y * 128;
    const int fl = lane & 15, fk = (lane >> 4) * 8;
    const int sr = t >> 1, sk = (t & 1) * 16;

    const ushort* arow = A  + (size_t)(m0 + sr) * 256;
    const ushort* brow = WT + (size_t)(n0 + sr) * 256;

    f32x4v acc[4][4];
    #pragma unroll
    for (int i = 0; i < 4; i++)
        #pragma unroll
        for (int j = 0; j < 4; j++) acc[i][j] = (f32x4v)(0.f);

    for (int k0 = 0; k0 < 256; k0 += 32) {
        const uint4* ap = (const uint4*)&arow[k0 + sk];
        *(uint4*)&As[sr * LDT + sk]     = ap[0];
        *(uint4*)&As[sr * LDT + sk + 8] = ap[1];
        const uint4* bp = (const uint4*)&brow[k0 + sk];
        *(uint4*)&Bs[sr * LDT + sk]     = bp[0];
        *(uint4*)&Bs[sr * LDT + sk + 8] = bp[1];
        __syncthreads();

        bf16x8 af[4], bfv[4];
        #pragma unroll
        for (int i = 0; i < 4; i++)
            af[i] = *(const bf16x8*)&As[(wm + i * 16 + fl) * LDT + fk];
        #pragma unroll
        for (int j = 0; j < 4; j++)
            bfv[j] = *(const bf16x8*)&Bs[(wn + j * 16 + fl) * LDT + fk];
        #pragma unroll
        for (int i = 0; i < 4; i++)
            #pragma unroll
            for (int j = 0; j < 4; j++)
                acc[i][j] = __builtin_amdgcn_mfma_f32_16x16x32_bf16(af[i], bfv[j], acc[i][j], 0, 0, 0);
        __syncthreads();
    }

    const int rb = (lane >> 4) * 4;
    #pragma unroll
    for (int j = 0; j < 4; j++) {
        const int col = n0 + wn + j * 16 + fl;
        const float bv = bias[col];
        #pragma unroll
        for (int i = 0; i < 4; i++) {
            #pragma unroll
            for (int r = 0; r < 4; r++) {
                const int row = m0 + wm + i * 16 + rb + r;
                out[(size_t)row * 256 + col] =
                    acc[i][j][r] + bv + query[(size_t)row * 256 + col];
            }
        }
    }
}

extern "C" void kernel_launch(void* const* d_in, const int* in_sizes, int n_in,
                              void* d_out, int out_size, void* d_ws, size_t ws_size,
                              hipStream_t stream) {
    const float* query      = (const float*)d_in[0];
    const float* value_feat = (const float*)d_in[2];
    const float* refp       = (const float*)d_in[3];
    const void*  bev        = d_in[4];
    const float* W_value    = (const float*)d_in[7];
    const float* b_value    = (const float*)d_in[8];
    const float* W_off      = (const float*)d_in[9];
    const float* b_off      = (const float*)d_in[10];
    const float* W_attn     = (const float*)d_in[11];
    const float* b_attn     = (const float*)d_in[12];
    const float* W_out      = (const float*)d_in[13];
    const float* b_out      = (const float*)d_in[14];

    float* ws      = (float*)d_ws;
    float* offn    = ws;                               // 4096*512 f32
    float* attnw   = offn + 2097152;                   // 4096*256 f32
    float* maskf   = attnw + 1048576;                  // 6*4096
    float* countf  = maskf + 24576;                    // 4096
    unsigned int* flag = (unsigned int*)(countf + 4096);
    float* logits  = countf + 4096 + 64;               // 4096*768 f32
    unsigned char* val = (unsigned char*)(logits + 3145728);  // 117360*256 fp8 (head-major)
    ushort* out_cam = (ushort*)(val + (size_t)MROWS * EMBED); // 6*4096*256 bf16
    ushort* Sbf    = out_cam + (size_t)CAMS * NQ * EMBED;     // 4096*256 bf16
    ushort* WTall  = Sbf + (size_t)NQ * EMBED;                // 1280*256 bf16

    detect_kernel<<<1, 256, 0, stream>>>((const unsigned int*)bev, flag);
    mask_kernel<<<16, 256, 0, stream>>>(bev, flag, maskf, countf);
    wtall_kernel<<<dim3(40, 8), 256, 0, stream>>>(W_off, W_attn, W_out, W_value, WTall);
    proj_gemm<<<dim3(6, 32), 256, 0, stream>>>(query, WTall, logits);
    proj_epi<<<NQ / 4, 256, 0, stream>>>(logits, b_off, b_attn, offn, attnw);
    gemm_mfma<<<3668, 256, 0, stream>>>(
        value_feat, WTall + (size_t)1024 * 256, b_value, val, MROWS);
    sample_kernel<<<CAMS * NQ / 4, 256, 0, stream>>>(refp, offn, attnw, val, maskf, out_cam);
    mean_kernel<<<NQ / 4, 256, 0, stream>>>(out_cam, maskf, countf, Sbf);
    out_gemm<<<dim3(2, 32), 256, 0, stream>>>(Sbf, WTall + (size_t)768 * 256, b_out, query, (float*)d_out);
}

// Round 20
// 181.278 us; speedup vs baseline: 1.0759x; 1.0759x over previous
//
#include <hip/hip_runtime.h>
#include <hip/hip_bf16.h>

#define NQ 4096
#define EMBED 256
#define HEADS 8
#define HEAD_DIM 32
#define LEVELS 4
#define POINTS 8
#define CAMS 6
#define LTOT 19560
#define MROWS (CAMS * LTOT)   // 117360

using bf16x8 = __attribute__((ext_vector_type(8))) __bf16;
using bf16x4 = __attribute__((ext_vector_type(4))) __bf16;
using f32x4v = __attribute__((ext_vector_type(4))) float;
using f32x2v = __attribute__((ext_vector_type(2))) float;

__device__ inline ushort f2bf(float f) {
    unsigned u = __builtin_bit_cast(unsigned, f);
    u += 0x7FFFu + ((u >> 16) & 1u);   // round-to-nearest-even
    return (ushort)(u >> 16);
}
__device__ inline float bflo(unsigned u) {
    return __builtin_bit_cast(float, u << 16);
}
__device__ inline float bfhi(unsigned u) {
    return __builtin_bit_cast(float, u & 0xFFFF0000u);
}
__device__ inline float bpermf(int addr, float v) {
    return __builtin_bit_cast(float, __builtin_amdgcn_ds_bpermute(addr, __builtin_bit_cast(int, v)));
}
__device__ inline unsigned bpermu(int addr, unsigned v) {
    return (unsigned)__builtin_amdgcn_ds_bpermute(addr, (int)v);
}
// fp8 e4m3 (OCP on gfx950) HW converts
__device__ inline unsigned char f2fp8(float f) {
    return (unsigned char)(__builtin_amdgcn_cvt_pk_fp8_f32(f, 0.f, 0, false) & 0xFF);
}

// ---------------------------------------------------------------------------
// Detect bev_mask element size (uint8 bools vs int32).
// ---------------------------------------------------------------------------
__global__ __launch_bounds__(256) void detect_kernel(const unsigned int* __restrict__ bm,
                                                     unsigned int* __restrict__ flag) {
    __shared__ unsigned int red[256];
    const int t = threadIdx.x;
    unsigned int acc = 0;
    for (int i = t; i < (CAMS * NQ * 4) / 4; i += 256)
        acc |= (bm[i] & 0xFFFFFF00u);
    red[t] = acc;
    __syncthreads();
    for (int s = 128; s > 0; s >>= 1) {
        if (t < s) red[t] |= red[t + s];
        __syncthreads();
    }
    if (t == 0) flag[0] = red[0] ? 1u : 0u;
}

__global__ __launch_bounds__(256) void mask_kernel(const void* __restrict__ bm,
                                                   const unsigned int* __restrict__ flag,
                                                   float* __restrict__ maskf,
                                                   float* __restrict__ countf) {
    const int q = blockIdx.x * 256 + threadIdx.x;
    if (q >= NQ) return;
    const bool u8 = (flag[0] != 0);
    float cnt = 0.f;
    #pragma unroll
    for (int c = 0; c < CAMS; c++) {
        bool hit;
        if (u8) {
            const unsigned int w = ((const unsigned int*)bm)[c * NQ + q];
            hit = (w != 0);
        } else {
            const int* p = (const int*)bm;
            int s = 0;
            #pragma unroll
            for (int d = 0; d < 4; d++) s |= p[(c * NQ + q) * 4 + d];
            hit = (s != 0);
        }
        maskf[c * NQ + q] = hit ? 1.f : 0.f;
        cnt += hit ? 1.f : 0.f;
    }
    countf[q] = fmaxf(cnt, 1.f);
}

// ---------------------------------------------------------------------------
// Build WTall [1280][256] bf16: transposed cols of (W_off | W_attn | W_out |
// W_value).
// ---------------------------------------------------------------------------
__global__ __launch_bounds__(256) void wtall_kernel(const float* __restrict__ W_off,
                                                    const float* __restrict__ W_attn,
                                                    const float* __restrict__ W_out,
                                                    const float* __restrict__ W_value,
                                                    ushort* __restrict__ WTall) {
    __shared__ float tile[32][33];
    const int bn = blockIdx.x;   // 40 n-tiles
    const int bk = blockIdx.y;   // 8 k-tiles
    const int t = threadIdx.x;
    const int r = t >> 5, c = t & 31;
    #pragma unroll
    for (int it = 0; it < 4; it++) {
        const int k = bk * 32 + it * 8 + r;
        const int n = bn * 32 + c;
        float v;
        if (n < 512)       v = W_off[(size_t)k * 512 + n];
        else if (n < 768)  v = W_attn[(size_t)k * 256 + (n - 512)];
        else if (n < 1024) v = W_out[(size_t)k * 256 + (n - 768)];
        else               v = W_value[(size_t)k * 256 + (n - 1024)];
        tile[it * 8 + r][c] = v;
    }
    __syncthreads();
    #pragma unroll
    for (int it = 0; it < 4; it++) {
        const int n = bn * 32 + it * 8 + r;
        const int k = bk * 32 + c;
        WTall[(size_t)n * 256 + k] = f2bf(tile[c][it * 8 + r]);
    }
}

// ---------------------------------------------------------------------------
// proj GEMM: logits[4096][768] = query @ (W_off|W_attn), raw.
// ---------------------------------------------------------------------------
#define LDT 40   // padded LDS stride (bf16)

__global__ __launch_bounds__(256) void proj_gemm(const float* __restrict__ A,
                                                 const ushort* __restrict__ WT,
                                                 float* __restrict__ C) {
    __shared__ ushort As[128 * LDT];
    __shared__ ushort Bs[128 * LDT];
    const int t = threadIdx.x;
    const int wave = t >> 6, lane = t & 63;
    const int wm = (wave & 1) * 64, wn = (wave >> 1) * 64;
    const int n0 = blockIdx.x * 128, m0 = blockIdx.y * 128;
    const int fl = lane & 15, fk = (lane >> 4) * 8;
    const int sr = t >> 1, sk = (t & 1) * 16;

    const float*  arow = A  + (size_t)(m0 + sr) * 256;
    const ushort* brow = WT + (size_t)(n0 + sr) * 256;

    f32x4v acc[4][4];
    #pragma unroll
    for (int i = 0; i < 4; i++)
        #pragma unroll
        for (int j = 0; j < 4; j++) acc[i][j] = (f32x4v)(0.f);

    for (int k0 = 0; k0 < 256; k0 += 32) {
        bf16x8 w0, w1;
        #pragma unroll
        for (int u = 0; u < 2; u++) {
            const float4 v = *(const float4*)&arow[k0 + sk + u * 4];
            w0[u * 4 + 0] = (__bf16)v.x; w0[u * 4 + 1] = (__bf16)v.y;
            w0[u * 4 + 2] = (__bf16)v.z; w0[u * 4 + 3] = (__bf16)v.w;
        }
        #pragma unroll
        for (int u = 0; u < 2; u++) {
            const float4 v = *(const float4*)&arow[k0 + sk + 8 + u * 4];
            w1[u * 4 + 0] = (__bf16)v.x; w1[u * 4 + 1] = (__bf16)v.y;
            w1[u * 4 + 2] = (__bf16)v.z; w1[u * 4 + 3] = (__bf16)v.w;
        }
        *(bf16x8*)&As[sr * LDT + sk]     = w0;
        *(bf16x8*)&As[sr * LDT + sk + 8] = w1;
        const uint4* bp = (const uint4*)&brow[k0 + sk];
        *(uint4*)&Bs[sr * LDT + sk]     = bp[0];
        *(uint4*)&Bs[sr * LDT + sk + 8] = bp[1];
        __syncthreads();

        bf16x8 af[4], bfv[4];
        #pragma unroll
        for (int i = 0; i < 4; i++)
            af[i] = *(const bf16x8*)&As[(wm + i * 16 + fl) * LDT + fk];
        #pragma unroll
        for (int j = 0; j < 4; j++)
            bfv[j] = *(const bf16x8*)&Bs[(wn + j * 16 + fl) * LDT + fk];
        #pragma unroll
        for (int i = 0; i < 4; i++)
            #pragma unroll
            for (int j = 0; j < 4; j++)
                acc[i][j] = __builtin_amdgcn_mfma_f32_16x16x32_bf16(af[i], bfv[j], acc[i][j], 0, 0, 0);
        __syncthreads();
    }

    const int rb = (lane >> 4) * 4;
    #pragma unroll
    for (int j = 0; j < 4; j++) {
        const int col = n0 + wn + j * 16 + fl;
        #pragma unroll
        for (int i = 0; i < 4; i++)
            #pragma unroll
            for (int r = 0; r < 4; r++)
                C[(size_t)(m0 + wm + i * 16 + rb + r) * 768 + col] = acc[i][j][r];
    }
}

// ---------------------------------------------------------------------------
// proj epilogue: offset normalize + per-head softmax. 4 queries/block.
// ---------------------------------------------------------------------------
__global__ __launch_bounds__(256) void proj_epi(const float* __restrict__ logits,
                                                const float* __restrict__ b_off,
                                                const float* __restrict__ b_attn,
                                                float* __restrict__ offn,
                                                float* __restrict__ attnw) {
    const int t = threadIdx.x;
    const int q0 = blockIdx.x * 4;
    const float Wl[4] = {160.f, 80.f, 40.f, 20.f};
    const float Hl[4] = {92.f, 46.f, 23.f, 12.f};
    const int j0 = t, j1 = t + 256;
    const int l0 = (j0 & 63) >> 4, l1 = (j1 & 63) >> 4;
    const float inv0 = 1.0f / ((j0 & 1) ? Hl[l0] : Wl[l0]);
    const float inv1 = 1.0f / ((j1 & 1) ? Hl[l1] : Wl[l1]);
    const float bo0 = b_off[j0], bo1 = b_off[j1], ba = b_attn[t];
    #pragma unroll
    for (int i = 0; i < 4; i++) {
        const float* lg = logits + (size_t)(q0 + i) * 768;
        offn[(size_t)(q0 + i) * 512 + j0] = (lg[j0] + bo0) * inv0;
        offn[(size_t)(q0 + i) * 512 + j1] = (lg[j1] + bo1) * inv1;
        const float v = lg[512 + t] + ba;
        float m = v;
        for (int s = 16; s > 0; s >>= 1) m = fmaxf(m, __shfl_xor(m, s, 32));
        const float e = expf(v - m);
        float ssum = e;
        for (int s = 16; s > 0; s >>= 1) ssum += __shfl_xor(ssum, s, 32);
        attnw[(size_t)(q0 + i) * 256 + t] = e / ssum;
    }
}

// ---------------------------------------------------------------------------
// Value projection GEMM v3b (f32 A, bf16 MFMA) -> FP8 e4m3 val.
// Coalesced one-shot A stage, swizzled LDS, B double-buffer, one barrier
// per K-step, LDS fp8 pack + coalesced 32B copy-out. Channel-major val.
// Grid 3668, XCD-pair swizzle.
// ---------------------------------------------------------------------------
#define GMT 64

__global__ __launch_bounds__(256) void gemm_mfma(const float* __restrict__ A,
                                                 const ushort* __restrict__ WT,
                                                 const float* __restrict__ bias,
                                                 unsigned char* __restrict__ C, int M) {
    __shared__ ushort AsF[GMT * 256];    // 32KB bf16, swizzled; reused as fp8 image
    __shared__ ushort Bsb[2][128 * 32];  // 2 x 8KB bf16, swizzled
    const int t = threadIdx.x;
    const int wave = t >> 6, lane = t & 63;
    const int wm = (wave & 1) * 32, wn = (wave >> 1) * 64;

    // XCD-pair swizzle: blocks w and w+8 (same XCD) = two n-halves of one m-tile
    const int w = blockIdx.x;
    int mt, nh;
    if (w < 3664) { mt = (w >> 4) * 8 + (w & 7); nh = (w >> 3) & 1; }
    else          { mt = 1832 + ((w - 3664) >> 1); nh = (w - 3664) & 1; }
    const int m0 = mt * GMT, n0 = nh * 128;

    const int fl = lane & 15, fk = (lane >> 4) * 8;

    // ---- A stage: 16 rounds, each 256 threads x 16B contiguous ----
    #pragma unroll 4
    for (int r = 0; r < 16; r++) {
        const int e = r * 1024 + t * 4;          // ushort idx in [64][256] tile
        const int row = e >> 8;
        int gr = m0 + row; if (gr >= M) gr = M - 1;
        const float4 v = *(const float4*)&A[(size_t)gr * 256 + (e & 255)];
        bf16x4 pk;
        pk[0] = (__bf16)v.x; pk[1] = (__bf16)v.y;
        pk[2] = (__bf16)v.z; pk[3] = (__bf16)v.w;
        *(bf16x4*)&AsF[e ^ ((row & 7) << 3)] = pk;
    }

    // ---- B stage buf0 (k0 = 0) ----
    const int rr = t >> 1, off = (t & 1) * 16;
    const ushort* bsrc = WT + (size_t)(n0 + rr) * 256 + off;
    const int bsw = (rr & 3) << 3;
    {
        const uint4 b0 = *(const uint4*)(bsrc);
        const uint4 b1 = *(const uint4*)(bsrc + 8);
        *(uint4*)&Bsb[0][(rr * 32 + off + 0) ^ bsw] = b0;
        *(uint4*)&Bsb[0][(rr * 32 + off + 8) ^ bsw] = b1;
    }
    __syncthreads();

    f32x4v acc[2][4];
    #pragma unroll
    for (int i = 0; i < 2; i++)
        #pragma unroll
        for (int j = 0; j < 4; j++) acc[i][j] = (f32x4v)(0.f);

    #pragma unroll
    for (int ks = 0; ks < 8; ks++) {
        const int cur = ks & 1;
        const int k0 = ks * 32;

        uint4 nb0, nb1;
        if (ks < 7) {
            nb0 = *(const uint4*)(bsrc + (k0 + 32));
            nb1 = *(const uint4*)(bsrc + (k0 + 32) + 8);
        }

        bf16x8 af[2], bfv[4];
        #pragma unroll
        for (int i = 0; i < 2; i++) {
            const int row = wm + i * 16 + fl;
            af[i] = *(const bf16x8*)&AsF[(row * 256 + k0 + fk) ^ ((fl & 7) << 3)];
        }
        #pragma unroll
        for (int j = 0; j < 4; j++) {
            const int br = wn + j * 16 + fl;
            bfv[j] = *(const bf16x8*)&Bsb[cur][(br * 32 + fk) ^ ((fl & 3) << 3)];
        }
        #pragma unroll
        for (int i = 0; i < 2; i++)
            #pragma unroll
            for (int j = 0; j < 4; j++)
                acc[i][j] = __builtin_amdgcn_mfma_f32_16x16x32_bf16(af[i], bfv[j], acc[i][j], 0, 0, 0);

        if (ks < 7) {
            *(uint4*)&Bsb[cur ^ 1][(rr * 32 + off + 0) ^ bsw] = nb0;
            *(uint4*)&Bsb[cur ^ 1][(rr * 32 + off + 8) ^ bsw] = nb1;
        }
        __syncthreads();
    }

    // ---- epilogue: pack fp8 into LDS image [64 rows][136 B stride] ----
    unsigned char* img = (unsigned char*)AsF;   // 64*136 = 8704 B <= 32 KB
    const int rb = (lane >> 4) * 4;
    #pragma unroll
    for (int j = 0; j < 4; j++) {
        const int col = wn + j * 16 + fl;
        const float bv = bias[n0 + col];
        #pragma unroll
        for (int i = 0; i < 2; i++) {
            #pragma unroll
            for (int r = 0; r < 4; r++) {
                const int row = wm + i * 16 + rb + r;
                img[row * 136 + col] = f2fp8(acc[i][j][r] + bv);
            }
        }
    }
    __syncthreads();

    // ---- coalesced copy-out: thread t -> row t/4, 32B chunk (t%4)*32 ----
    {
        const int row = t >> 2, cb = (t & 3) * 32;
        const int grow = m0 + row;
        if (grow < M) {
            const uint4 w0v = *(const uint4*)&img[row * 136 + cb];
            const uint4 w1v = *(const uint4*)&img[row * 136 + cb + 16];
            unsigned char* dst = C + (size_t)grow * 256 + n0 + cb;
            *(uint4*)dst = w0v;
            *(uint4*)(dst + 16) = w1v;
        }
    }
}

// ---------------------------------------------------------------------------
// Sampling helpers (inline, fully unrolled -> registers).
// ---------------------------------------------------------------------------
__device__ __forceinline__ void bperm_batch(int aP0, int aP1,
                                            const float* wts, const unsigned* rowB,
                                            float* w, unsigned* ro) {
    #pragma unroll
    for (int c = 0; c < 4; c++) {
        w[c]     = bpermf(aP0, wts[c]);
        ro[c]    = bpermu(aP0, rowB[c]);
        w[4 + c] = bpermf(aP1, wts[c]);
        ro[4 + c] = bpermu(aP1, rowB[c]);
    }
}
__device__ __forceinline__ void load_batch8(const char* base, const unsigned* ro, unsigned* vv) {
    #pragma unroll
    for (int c = 0; c < 8; c++)
        vv[c] = *(const unsigned*)(base + ro[c]);
}
__device__ __forceinline__ void acc_batch8(const float* w, const unsigned* vv,
                                           float2& a01, float2& a23) {
    #pragma unroll
    for (int c = 0; c < 8; c++) {
        const float wt = w[c];
        const f32x2v lo = __builtin_amdgcn_cvt_pk_f32_fp8(vv[c], false);
        const f32x2v hi = __builtin_amdgcn_cvt_pk_f32_fp8(vv[c], true);
        a01.x += wt * lo.x; a01.y += wt * lo.y;
        a23.x += wt * hi.x; a23.y += wt * hi.y;
    }
}

// ---------------------------------------------------------------------------
// Deformable bilinear sampling over FP8 val. One WAVE per (cam,q):
// 8 heads x 8 lanes, lane owns 4 channels (4B gathers).
// bpermute-deduped weight math + 2-stage pipelined batches.
// ---------------------------------------------------------------------------
__global__ __launch_bounds__(256) void sample_kernel(const float* __restrict__ refp,
                                                     const float* __restrict__ offn,
                                                     const float* __restrict__ attnw,
                                                     const unsigned char* __restrict__ val,
                                                     const float* __restrict__ maskf,
                                                     ushort* __restrict__ out_cam) {
    const int wv = threadIdx.x >> 6, lane = threadIdx.x & 63;
    const int pair = blockIdx.x * 4 + wv;
    const int cam = pair >> 12;
    const int q = pair & (NQ - 1);

    const int h = lane >> 3, dg = lane & 7;
    ushort* dst = &out_cam[((size_t)cam * NQ + q) * EMBED + h * HEAD_DIM + dg * 4];
    const float mk = maskf[cam * NQ + q];
    if (mk == 0.f) {                       // wave-uniform
        ushort4 z; z.x = 0; z.y = 0; z.z = 0; z.w = 0;
        *(ushort4*)dst = z;
        return;
    }

    const unsigned hd = (unsigned)(h * HEAD_DIM + dg * 4);   // channel byte offset (fp8)
    const float* refq = refp + ((size_t)cam * NQ + q) * 8;
    const float* offq = offn + (size_t)q * 512 + h * 64;
    const float* attq = attnw + (size_t)q * 256 + h * 32;
    const char* camLane = (const char*)val + (size_t)cam * (LTOT * EMBED) + hd;

    const float rx = refq[2 * (dg & 3)], ry = refq[2 * (dg & 3) + 1];
    const int grp4 = (lane & 56) * 4;      // bpermute byte-addr base of group

    const int Hs[4] = {92, 46, 23, 12};
    const int Ws[4] = {160, 80, 40, 20};
    const int st[4] = {0, 14720, 18400, 19320};

    float2 a01 = {0.f, 0.f}, a23 = {0.f, 0.f};
    #pragma unroll
    for (int l = 0; l < LEVELS; l++) {
        const int H = Hs[l], W = Ws[l];
        const float fW = (float)W, fH = (float)H;

        // ---- own-point weight/address compute (1 point per lane) ----
        float wts[4];
        unsigned rowB[4];
        {
            const float x = (rx + offq[l * 16 + dg * 2]) * fW - 0.5f;
            const float y = (ry + offq[l * 16 + dg * 2 + 1]) * fH - 0.5f;
            const float x0f = floorf(x), y0f = floorf(y);
            const float lx = x - x0f, ly = y - y0f;
            const int x0 = (int)x0f, y0 = (int)y0f, x1 = x0 + 1, y1 = y0 + 1;
            const float aw = attq[l * 8 + dg];
            const bool vx0 = (unsigned)x0 < (unsigned)W;
            const bool vx1 = (unsigned)x1 < (unsigned)W;
            const bool vy0 = (unsigned)y0 < (unsigned)H;
            const bool vy1 = (unsigned)y1 < (unsigned)H;
            const float hx = lx * aw, gx = aw - hx;
            wts[0] = (vx0 & vy0) ? gx * (1.f - ly) : 0.f;
            wts[1] = (vx1 & vy0) ? hx * (1.f - ly) : 0.f;
            wts[2] = (vx0 & vy1) ? gx * ly : 0.f;
            wts[3] = (vx1 & vy1) ? hx * ly : 0.f;
            const int cx0 = min(max(x0, 0), W - 1), cx1 = min(max(x1, 0), W - 1);
            const int cy0 = min(max(y0, 0), H - 1), cy1 = min(max(y1, 0), H - 1);
            const unsigned r0 = (unsigned)(st[l] + cy0 * W), r1 = (unsigned)(st[l] + cy1 * W);
            rowB[0] = (r0 + cx0) * EMBED;
            rowB[1] = (r0 + cx1) * EMBED;
            rowB[2] = (r1 + cx0) * EMBED;
            rowB[3] = (r1 + cx1) * EMBED;
        }

        // ---- 2-stage pipelined batches: issue next before accumulating ----
        float w0[8], w1[8];
        unsigned ro0[8], ro1[8];
        unsigned vv0[8], vv1[8];

        bperm_batch(grp4 + 0 * 4, grp4 + 1 * 4, wts, rowB, w0, ro0);  // pts 0,1
        load_batch8(camLane, ro0, vv0);
        bperm_batch(grp4 + 2 * 4, grp4 + 3 * 4, wts, rowB, w1, ro1);  // pts 2,3
        load_batch8(camLane, ro1, vv1);
        acc_batch8(w0, vv0, a01, a23);
        bperm_batch(grp4 + 4 * 4, grp4 + 5 * 4, wts, rowB, w0, ro0);  // pts 4,5
        load_batch8(camLane, ro0, vv0);
        acc_batch8(w1, vv1, a01, a23);
        bperm_batch(grp4 + 6 * 4, grp4 + 7 * 4, wts, rowB, w1, ro1);  // pts 6,7
        load_batch8(camLane, ro1, vv1);
        acc_batch8(w0, vv0, a01, a23);
        acc_batch8(w1, vv1, a01, a23);
    }
    ushort4 o;
    o.x = __builtin_bit_cast(ushort, (__bf16)a01.x);
    o.y = __builtin_bit_cast(ushort, (__bf16)a01.y);
    o.z = __builtin_bit_cast(ushort, (__bf16)a23.x);
    o.w = __builtin_bit_cast(ushort, (__bf16)a23.y);
    *(ushort4*)dst = o;
}

// ---------------------------------------------------------------------------
// Masked mean over cams (bf16 out_cam) -> Sbf bf16. One wave per query.
// ---------------------------------------------------------------------------
__global__ __launch_bounds__(256) void mean_kernel(const ushort* __restrict__ out_cam,
                                                   const float* __restrict__ maskf,
                                                   const float* __restrict__ countf,
                                                   ushort* __restrict__ Sbf) {
    const int wv = threadIdx.x >> 6, lane = threadIdx.x & 63;
    const int q = blockIdx.x * 4 + wv;
    const int c4 = lane * 4;
    float4 acc = make_float4(0.f, 0.f, 0.f, 0.f);
    #pragma unroll
    for (int c = 0; c < CAMS; c++) {
        const float m = maskf[c * NQ + q];
        const uint2 v = *(const uint2*)&out_cam[(((size_t)c * NQ + q) << 8) + c4];
        acc.x += m * bflo(v.x); acc.y += m * bfhi(v.x);
        acc.z += m * bflo(v.y); acc.w += m * bfhi(v.y);
    }
    const float inv = 1.0f / countf[q];
    ushort4 s;
    s.x = __builtin_bit_cast(ushort, (__bf16)(acc.x * inv));
    s.y = __builtin_bit_cast(ushort, (__bf16)(acc.y * inv));
    s.z = __builtin_bit_cast(ushort, (__bf16)(acc.z * inv));
    s.w = __builtin_bit_cast(ushort, (__bf16)(acc.w * inv));
    *(ushort4*)&Sbf[(size_t)q * 256 + c4] = s;
}

// ---------------------------------------------------------------------------
// Output GEMM: out = Sbf @ W_out + b_out + query.
// ---------------------------------------------------------------------------
__global__ __launch_bounds__(256) void out_gemm(const ushort* __restrict__ A,
                                                const ushort* __restrict__ WT,
                                                const float* __restrict__ bias,
                                                const float* __restrict__ query,
                                                float* __restrict__ out) {
    __shared__ ushort As[128 * LDT];
    __shared__ ushort Bs[128 * LDT];
    const int t = threadIdx.x;
    const int wave = t >> 6, lane = t & 63;
    const int wm = (wave & 1) * 64, wn = (wave >> 1) * 64;
    const int n0 = blockIdx.x * 128, m0 = blockIdx.y * 128;
    const int fl = lane & 15, fk = (lane >> 4) * 8;
    const int sr = t >> 1, sk = (t & 1) * 16;

    const ushort* arow = A  + (size_t)(m0 + sr) * 256;
    const ushort* brow = WT + (size_t)(n0 + sr) * 256;

    f32x4v acc[4][4];
    #pragma unroll
    for (int i = 0; i < 4; i++)
        #pragma unroll
        for (int j = 0; j < 4; j++) acc[i][j] = (f32x4v)(0.f);

    for (int k0 = 0; k0 < 256; k0 += 32) {
        const uint4* ap = (const uint4*)&arow[k0 + sk];
        *(uint4*)&As[sr * LDT + sk]     = ap[0];
        *(uint4*)&As[sr * LDT + sk + 8] = ap[1];
        const uint4* bp = (const uint4*)&brow[k0 + sk];
        *(uint4*)&Bs[sr * LDT + sk]     = bp[0];
        *(uint4*)&Bs[sr * LDT + sk + 8] = bp[1];
        __syncthreads();

        bf16x8 af[4], bfv[4];
        #pragma unroll
        for (int i = 0; i < 4; i++)
            af[i] = *(const bf16x8*)&As[(wm + i * 16 + fl) * LDT + fk];
        #pragma unroll
        for (int j = 0; j < 4; j++)
            bfv[j] = *(const bf16x8*)&Bs[(wn + j * 16 + fl) * LDT + fk];
        #pragma unroll
        for (int i = 0; i < 4; i++)
            #pragma unroll
            for (int j = 0; j < 4; j++)
                acc[i][j] = __builtin_amdgcn_mfma_f32_16x16x32_bf16(af[i], bfv[j], acc[i][j], 0, 0, 0);
        __syncthreads();
    }

    const int rb = (lane >> 4) * 4;
    #pragma unroll
    for (int j = 0; j < 4; j++) {
        const int col = n0 + wn + j * 16 + fl;
        const float bv = bias[col];
        #pragma unroll
        for (int i = 0; i < 4; i++) {
            #pragma unroll
            for (int r = 0; r < 4; r++) {
                const int row = m0 + wm + i * 16 + rb + r;
                out[(size_t)row * 256 + col] =
                    acc[i][j][r] + bv + query[(size_t)row * 256 + col];
            }
        }
    }
}

extern "C" void kernel_launch(void* const* d_in, const int* in_sizes, int n_in,
                              void* d_out, int out_size, void* d_ws, size_t ws_size,
                              hipStream_t stream) {
    const float* query      = (const float*)d_in[0];
    const float* value_feat = (const float*)d_in[2];
    const float* refp       = (const float*)d_in[3];
    const void*  bev        = d_in[4];
    const float* W_value    = (const float*)d_in[7];
    const float* b_value    = (const float*)d_in[8];
    const float* W_off      = (const float*)d_in[9];
    const float* b_off      = (const float*)d_in[10];
    const float* W_attn     = (const float*)d_in[11];
    const float* b_attn     = (const float*)d_in[12];
    const float* W_out      = (const float*)d_in[13];
    const float* b_out      = (const float*)d_in[14];

    float* ws      = (float*)d_ws;
    float* offn    = ws;                               // 4096*512 f32
    float* attnw   = offn + 2097152;                   // 4096*256 f32
    float* maskf   = attnw + 1048576;                  // 6*4096
    float* countf  = maskf + 24576;                    // 4096
    unsigned int* flag = (unsigned int*)(countf + 4096);
    float* logits  = countf + 4096 + 64;               // 4096*768 f32
    unsigned char* val = (unsigned char*)(logits + 3145728);  // 117360*256 fp8
    ushort* out_cam = (ushort*)(val + (size_t)MROWS * EMBED); // 6*4096*256 bf16
    ushort* Sbf    = out_cam + (size_t)CAMS * NQ * EMBED;     // 4096*256 bf16
    ushort* WTall  = Sbf + (size_t)NQ * EMBED;                // 1280*256 bf16

    detect_kernel<<<1, 256, 0, stream>>>((const unsigned int*)bev, flag);
    mask_kernel<<<16, 256, 0, stream>>>(bev, flag, maskf, countf);
    wtall_kernel<<<dim3(40, 8), 256, 0, stream>>>(W_off, W_attn, W_out, W_value, WTall);
    proj_gemm<<<dim3(6, 32), 256, 0, stream>>>(query, WTall, logits);
    proj_epi<<<NQ / 4, 256, 0, stream>>>(logits, b_off, b_attn, offn, attnw);
    gemm_mfma<<<3668, 256, 0, stream>>>(
        value_feat, WTall + (size_t)1024 * 256, b_value, val, MROWS);
    sample_kernel<<<CAMS * NQ / 4, 256, 0, stream>>>(refp, offn, attnw, val, maskf, out_cam);
    mean_kernel<<<NQ / 4, 256, 0, stream>>>(out_cam, maskf, countf, Sbf);
    out_gemm<<<dim3(2, 32), 256, 0, stream>>>(Sbf, WTall + (size_t)768 * 256, b_out, query, (float*)d_out);
}